// Round 8
// baseline (121.709 us; speedup 1.0000x reference)
//
#include <hip/hip_runtime.h>
#include <stdint.h>

// inputs [B=64, T=256, D=1024] f32; tanh -> sequential dual-threshold
// integrate-and-fire scan over T per (b,d).
//
// Round-8: R5's T-pipeline deepened to 16 stages to get 1KB DRAM granule
// WITHOUT losing TLP (the confound in every previous granule test):
//   block = 1024 threads = 16 waves, covers 256 consecutive sequences;
//   wave k owns t in [16k,16k+16); lane L owns d-quad 4L..4L+3.
//   -> every global op is dwordx4 with 64 lanes x 16B = 1KB CONTIGUOUS
//      (vs 256B granule in R1/R5, which ran at ~2-3 TB/s effective).
//   grid = 256 blocks = 4096 waves = 16/CU = 4/SIMD (same TLP as R5).
// v-state hops wave->wave via LDS acquire/release flag (intra-block only
// -> co-residency guaranteed, no deadlock). 4 seqs/lane scan chains are
// ILP-independent; serial section ~16 x 0.2us, off the memory phases.
#define B_DIM 64
#define T_STEPS 256
#define D_DIM 1024
#define TPB 1024
#define NWAVE 16                // pipeline stages per block
#define SEQ_PER_BLK 256         // 4 seqs per lane x 64 lanes
#define TW 16                   // timesteps per wave (T/16)

typedef float f32x4 __attribute__((ext_vector_type(4)));

// XLA/Eigen f32 tanh rational approximation — bit-exact vs jnp.tanh
// (verified: absmax = 0.0). DO NOT change the FMA structure.
__device__ __forceinline__ float xla_tanhf(float x) {
    const float kClamp = 7.90531110763549805f;
    float xc = fminf(fmaxf(x, -kClamp), kClamp);
    float x2 = xc * xc;
    float p = __builtin_fmaf(x2, -2.76076847742355e-16f, 2.00018790482477e-13f);
    p = __builtin_fmaf(x2, p, -8.60467152213735e-11f);
    p = __builtin_fmaf(x2, p, 5.12229709037114e-08f);
    p = __builtin_fmaf(x2, p, 1.48572235717979e-05f);
    p = __builtin_fmaf(x2, p, 6.37261928875436e-04f);
    p = __builtin_fmaf(x2, p, 4.89352455891786e-03f);
    p = xc * p;
    float q = __builtin_fmaf(x2, 1.19825839466702e-06f, 1.18534705686654e-04f);
    q = __builtin_fmaf(x2, q, 2.26843463243900e-03f);
    q = __builtin_fmaf(x2, q, 4.89352518554385e-03f);
    float r = p / q;           // IEEE divide — required for bit-exactness
    return (fabsf(x) < 0.0004f) ? x : r;
}

// --- raw-asm building blocks ---------------------------------------------
// One dwordx4 load (lane's 4 adjacent d of one timestep) + advance voff by
// one timestep (D_DIM*4 = 4096 B). saddr form: addr = SGPR base +
// zext(voff); tensor is 64 MB so 32-bit offsets fit. 16B-aligned (d%4==0).
#define LD(i) "global_load_dwordx4 %" #i ", %16, %17\n\t" \
              "v_add_u32 %16, 0x1000, %16\n\t"

// Issue 16 loads (this wave's 16 timesteps) into 16-quad slice B.
#define ISSUE16(B) asm volatile( \
    LD(0) LD(1) LD(2) LD(3) LD(4) LD(5) LD(6) LD(7) \
    LD(8) LD(9) LD(10) LD(11) LD(12) LD(13) LD(14) LD(15) \
    : "=v"(B[0]), "=v"(B[1]), "=v"(B[2]), "=v"(B[3]), \
      "=v"(B[4]), "=v"(B[5]), "=v"(B[6]), "=v"(B[7]), \
      "=v"(B[8]), "=v"(B[9]), "=v"(B[10]), "=v"(B[11]), \
      "=v"(B[12]), "=v"(B[13]), "=v"(B[14]), "=v"(B[15]), \
      "+v"(voffi) \
    : "s"(inp_u) : "memory")

// Wait until <= CNT vmem ops outstanding; "+v" on the 4-quad sub-slice
// makes every use data-dependent on this wait. Only loads are in the
// queue during the tanh phase (stores all happen later).
#define WAIT4(CNT, Q0,Q1,Q2,Q3) asm volatile("s_waitcnt vmcnt(" CNT ")" \
    : "+v"(Q0), "+v"(Q1), "+v"(Q2), "+v"(Q3) :: "memory")

// Opaque keep-alive: pins tanh results so the compiler cannot sink the
// tanh chains below the spin loop.
#define KEEP4(Q0,Q1,Q2,Q3) asm volatile("" \
    : "+v"(Q0), "+v"(Q1), "+v"(Q2), "+v"(Q3))

#define TANH1(Q) { Q.x = xla_tanhf(Q.x); Q.y = xla_tanhf(Q.y); \
                   Q.z = xla_tanhf(Q.z); Q.w = xla_tanhf(Q.w); }

// tanh one 4-timestep sub-slice (16 values) after its wait.
#define TANH4(B, base) do { \
    TANH1(B[base+0]) TANH1(B[base+1]) TANH1(B[base+2]) TANH1(B[base+3]) \
    KEEP4(B[base+0], B[base+1], B[base+2], B[base+3]); } while (0)

// One scan step for one sequence component (bit-exact op order).
#define SSTEP(R, V, O) { \
    V = __builtin_fmaf(R, 0.01f, V); \
    float sp = (V >= 1.0f)  ? 1.0f : 0.0f; \
    float sn = (V <= -1.0f) ? 1.0f : 0.0f; \
    V = (V - sp) + sn; \
    O = (sp - sn) * 100.0f; }

// Scan all 16 timesteps in place for the lane's 4 sequences. The 4
// chains (v0..v3) are independent -> ILP covers the 9-op dependency.
#define SCAN16(B) do { \
    _Pragma("unroll") \
    for (int u = 0; u < TW; ++u) { \
        float r0 = B[u].x, r1 = B[u].y, r2 = B[u].z, r3 = B[u].w; \
        SSTEP(r0, v0, B[u].x); \
        SSTEP(r1, v1, B[u].y); \
        SSTEP(r2, v2, B[u].z); \
        SSTEP(r3, v3, B[u].w); \
    } } while (0)

// 16 nontemporal dwordx4 stores (after handoff — nothing waits on vmcnt
// afterwards, so retire latency is off the critical path; nt keeps the
// output stream from evicting L3-resident input). 1KB contiguous each.
#define ST(i) "global_store_dwordx4 %0, %" #i ", %17 nt\n\t" \
              "v_add_u32 %0, 0x1000, %0\n\t"
#define STORE16(B) asm volatile( \
    ST(1) ST(2) ST(3) ST(4) ST(5) ST(6) ST(7) ST(8) \
    ST(9) ST(10) ST(11) ST(12) ST(13) ST(14) ST(15) ST(16) \
    : "+v"(voffo) \
    : "v"(B[0]), "v"(B[1]), "v"(B[2]), "v"(B[3]), \
      "v"(B[4]), "v"(B[5]), "v"(B[6]), "v"(B[7]), \
      "v"(B[8]), "v"(B[9]), "v"(B[10]), "v"(B[11]), \
      "v"(B[12]), "v"(B[13]), "v"(B[14]), "v"(B[15]), "s"(outp_u) \
    : "memory")

__global__ __launch_bounds__(TPB)
void spike_scan_kernel(const float* __restrict__ in, float* __restrict__ out) {
    __shared__ float vstate[NWAVE - 1][SEQ_PER_BLK];  // v: stage k -> k+1
    __shared__ unsigned int flag[NWAVE];

    const int lane = threadIdx.x & 63;
    const int wk   = threadIdx.x >> 6;         // pipeline stage 0..15

    if (threadIdx.x < NWAVE) flag[threadIdx.x] = 0u;
    __syncthreads();

    // Block covers 256 consecutive sequences of one b (4 blocks per b).
    // Lane L owns d = dbase + 4L + {0,1,2,3}; wave k owns t in [16k,16k+16).
    const uint32_t b     = (uint32_t)blockIdx.x >> 2;
    const uint32_t dbase = ((uint32_t)blockIdx.x & 3u) << 8;
    uint32_t voffi = b * (T_STEPS * D_DIM * 4u)
                   + (uint32_t)wk * (TW * D_DIM * 4u)
                   + (dbase + 4u * (uint32_t)lane) * 4u;
    uint32_t voffo = voffi;
    const uint64_t inp_u  = (uint64_t)in;
    const uint64_t outp_u = (uint64_t)out;

    f32x4 rT[TW];                              // 16 timesteps x 4 seqs

    // Issue all 16 loads (16KB/wave in flight; 4096 waves -> whole input
    // stream in flight GPU-wide), then tanh sub-slices as they land.
    ISSUE16(rT);
    WAIT4("12", rT[0],  rT[1],  rT[2],  rT[3]);  TANH4(rT, 0);
    WAIT4("8",  rT[4],  rT[5],  rT[6],  rT[7]);  TANH4(rT, 4);
    WAIT4("4",  rT[8],  rT[9],  rT[10], rT[11]); TANH4(rT, 8);
    WAIT4("0",  rT[12], rT[13], rT[14], rT[15]); TANH4(rT, 12);

    // --- serial section: only the 9-op v-chains (4 ILP-parallel) ---
    float v0 = 0.0f, v1 = 0.0f, v2 = 0.0f, v3 = 0.0f;
    if (wk != 0) {
        while (__hip_atomic_load(&flag[wk - 1], __ATOMIC_ACQUIRE,
                                 __HIP_MEMORY_SCOPE_WORKGROUP) == 0u)
            __builtin_amdgcn_s_sleep(1);
        v0 = vstate[wk - 1][4 * lane + 0];
        v1 = vstate[wk - 1][4 * lane + 1];
        v2 = vstate[wk - 1][4 * lane + 2];
        v3 = vstate[wk - 1][4 * lane + 3];
    }
    SCAN16(rT);
    if (wk != NWAVE - 1) {
        vstate[wk][4 * lane + 0] = v0;
        vstate[wk][4 * lane + 1] = v1;
        vstate[wk][4 * lane + 2] = v2;
        vstate[wk][4 * lane + 3] = v3;
        __hip_atomic_store(&flag[wk], 1u, __ATOMIC_RELEASE,
                           __HIP_MEMORY_SCOPE_WORKGROUP);
    }
    // --- end serial section; stores off the critical chain ---

    STORE16(rT);
}

extern "C" void kernel_launch(void* const* d_in, const int* in_sizes, int n_in,
                              void* d_out, int out_size, void* d_ws, size_t ws_size,
                              hipStream_t stream) {
    const float* in = (const float*)d_in[0];
    float* out = (float*)d_out;
    dim3 block(TPB);
    dim3 grid((B_DIM * D_DIM) / SEQ_PER_BLK);   // 256 blocks = 4096 waves
    spike_scan_kernel<<<grid, block, 0, stream>>>(in, out);
}

// Round 9
// 113.613 us; speedup vs baseline: 1.0713x; 1.0713x over previous
//
#include <hip/hip_runtime.h>
#include <stdint.h>

// inputs [B=64, T=256, D=1024] f32; tanh -> sequential dual-threshold
// integrate-and-fire scan over T per (b,d).
//
// FINAL (R5 structure, best measured: 109.6us): intra-block T-pipeline.
// Only the 9-op v-chain is sequential; loads and tanh are not. Block =
// 4 waves over the SAME 64 sequences; wave k owns timesteps [64k,64k+64).
// 4096 waves = 16/CU. v-state hops wave->wave via LDS acquire/release
// flag (intra-block only -> co-residency guaranteed, no deadlock).
//
// Session ledger (8 rounds, all absmax=0.0): prefetch lead depth null
// (R0); store policy null (R3/R6); access width regress (R2/R4); TLP
// 1->4 waves/SIMD +1us (R5, best); tail overlap regress (R6); DRAM
// granule 256B->1KB with TLP controlled regress (R7/R8). dur_us floor =
// ~86us harness poison fills + ~21.3us kernel bytes-floor at 6.3 TB/s;
// this kernel sits ~2% above that composite floor.
#define B_DIM 64
#define T_STEPS 256
#define D_DIM 1024
#define TPB 256
#define SEQ_PER_BLK 64          // one wave-width of sequences per block
#define TQ 64                   // timesteps per wave (T/4)

// XLA/Eigen f32 tanh rational approximation — bit-exact vs jnp.tanh
// (verified: absmax = 0.0). DO NOT change the FMA structure.
__device__ __forceinline__ float xla_tanhf(float x) {
    const float kClamp = 7.90531110763549805f;
    float xc = fminf(fmaxf(x, -kClamp), kClamp);
    float x2 = xc * xc;
    float p = __builtin_fmaf(x2, -2.76076847742355e-16f, 2.00018790482477e-13f);
    p = __builtin_fmaf(x2, p, -8.60467152213735e-11f);
    p = __builtin_fmaf(x2, p, 5.12229709037114e-08f);
    p = __builtin_fmaf(x2, p, 1.48572235717979e-05f);
    p = __builtin_fmaf(x2, p, 6.37261928875436e-04f);
    p = __builtin_fmaf(x2, p, 4.89352455891786e-03f);
    p = xc * p;
    float q = __builtin_fmaf(x2, 1.19825839466702e-06f, 1.18534705686654e-04f);
    q = __builtin_fmaf(x2, q, 2.26843463243900e-03f);
    q = __builtin_fmaf(x2, q, 4.89352518554385e-03f);
    float r = p / q;           // IEEE divide — required for bit-exactness
    return (fabsf(x) < 0.0004f) ? x : r;
}

// --- raw-asm building blocks ---------------------------------------------
// One load + advance voff by one timestep (D_DIM*4 = 4096 B). saddr form:
// addr = SGPR base + zext(voff); tensor is 64 MB so 32-bit offsets fit.
#define LD(i) "global_load_dword %" #i ", %16, %17\n\t" \
              "v_add_u32 %16, 0x1000, %16\n\t"

// Issue 16 loads into 16-reg slice B; compiler never sees them as memory
// ops -> no auto-waitcnt; vmcnt tracked manually.
#define ISSUE16(B) asm volatile( \
    LD(0) LD(1) LD(2) LD(3) LD(4) LD(5) LD(6) LD(7) \
    LD(8) LD(9) LD(10) LD(11) LD(12) LD(13) LD(14) LD(15) \
    : "=v"(B[0]), "=v"(B[1]), "=v"(B[2]), "=v"(B[3]), \
      "=v"(B[4]), "=v"(B[5]), "=v"(B[6]), "=v"(B[7]), \
      "=v"(B[8]), "=v"(B[9]), "=v"(B[10]), "=v"(B[11]), \
      "=v"(B[12]), "=v"(B[13]), "=v"(B[14]), "=v"(B[15]), \
      "+v"(voffi) \
    : "s"(inp_u) : "memory")

// Wait until <= CNT vmem ops outstanding; "+v" on the slice makes every
// use data-dependent on this wait. Only loads are in the queue during the
// tanh phase (all stores happen after), so vmcnt(0) at the tail is safe.
#define WAITBUF(B, CNT) asm volatile("s_waitcnt vmcnt(" CNT ")" \
    : "+v"(B[0]), "+v"(B[1]), "+v"(B[2]), "+v"(B[3]), \
      "+v"(B[4]), "+v"(B[5]), "+v"(B[6]), "+v"(B[7]), \
      "+v"(B[8]), "+v"(B[9]), "+v"(B[10]), "+v"(B[11]), \
      "+v"(B[12]), "+v"(B[13]), "+v"(B[14]), "+v"(B[15]) \
    :: "memory")

// Opaque keep-alive: pins the tanh results as "computed here" so the
// compiler cannot sink the tanh chains below the (volatile) spin loop —
// asm volatile blocks are not reordered across atomic ops.
#define KEEP16(B) asm volatile("" \
    : "+v"(B[0]), "+v"(B[1]), "+v"(B[2]), "+v"(B[3]), \
      "+v"(B[4]), "+v"(B[5]), "+v"(B[6]), "+v"(B[7]), \
      "+v"(B[8]), "+v"(B[9]), "+v"(B[10]), "+v"(B[11]), \
      "+v"(B[12]), "+v"(B[13]), "+v"(B[14]), "+v"(B[15]))

#define TANH16(B) do { \
    _Pragma("unroll") \
    for (int u = 0; u < 16; ++u) B[u] = xla_tanhf(B[u]); \
    KEEP16(B); } while (0)

// Scan 16 steps in place: consumes tanh value B[u], leaves output in B[u].
// Bit-exact op order preserved from the verified kernel: the *0.01 stays
// fused in the fma (precomputing r*DT would change rounding).
#define SCAN16(B) do { \
    _Pragma("unroll") \
    for (int u = 0; u < 16; ++u) { \
        float r = B[u]; \
        v = __builtin_fmaf(r, 0.01f, v); \
        float sp = (v >= 1.0f)  ? 1.0f : 0.0f; \
        float sn = (v <= -1.0f) ? 1.0f : 0.0f; \
        v = (v - sp) + sn; \
        B[u] = (sp - sn) * 100.0f; \
    } } while (0)

// 16 nontemporal stores (after handoff — nothing ever waits on vmcnt
// again, so store retire latency is fully off the critical path; nt keeps
// the output stream from evicting the L3-resident input).
#define STORE16(B) asm volatile( \
    "global_store_dword %16, %0, %17 nt\n\t"  "v_add_u32 %16, 0x1000, %16\n\t" \
    "global_store_dword %16, %1, %17 nt\n\t"  "v_add_u32 %16, 0x1000, %16\n\t" \
    "global_store_dword %16, %2, %17 nt\n\t"  "v_add_u32 %16, 0x1000, %16\n\t" \
    "global_store_dword %16, %3, %17 nt\n\t"  "v_add_u32 %16, 0x1000, %16\n\t" \
    "global_store_dword %16, %4, %17 nt\n\t"  "v_add_u32 %16, 0x1000, %16\n\t" \
    "global_store_dword %16, %5, %17 nt\n\t"  "v_add_u32 %16, 0x1000, %16\n\t" \
    "global_store_dword %16, %6, %17 nt\n\t"  "v_add_u32 %16, 0x1000, %16\n\t" \
    "global_store_dword %16, %7, %17 nt\n\t"  "v_add_u32 %16, 0x1000, %16\n\t" \
    "global_store_dword %16, %8, %17 nt\n\t"  "v_add_u32 %16, 0x1000, %16\n\t" \
    "global_store_dword %16, %9, %17 nt\n\t"  "v_add_u32 %16, 0x1000, %16\n\t" \
    "global_store_dword %16, %10, %17 nt\n\t" "v_add_u32 %16, 0x1000, %16\n\t" \
    "global_store_dword %16, %11, %17 nt\n\t" "v_add_u32 %16, 0x1000, %16\n\t" \
    "global_store_dword %16, %12, %17 nt\n\t" "v_add_u32 %16, 0x1000, %16\n\t" \
    "global_store_dword %16, %13, %17 nt\n\t" "v_add_u32 %16, 0x1000, %16\n\t" \
    "global_store_dword %16, %14, %17 nt\n\t" "v_add_u32 %16, 0x1000, %16\n\t" \
    "global_store_dword %16, %15, %17 nt\n\t" "v_add_u32 %16, 0x1000, %16\n\t" \
    :: "v"(B[0]), "v"(B[1]), "v"(B[2]), "v"(B[3]), \
       "v"(B[4]), "v"(B[5]), "v"(B[6]), "v"(B[7]), \
       "v"(B[8]), "v"(B[9]), "v"(B[10]), "v"(B[11]), \
       "v"(B[12]), "v"(B[13]), "v"(B[14]), "v"(B[15]), \
       "v"(voffo), "s"(outp_u) : "memory")

__global__ __launch_bounds__(TPB)
void spike_scan_kernel(const float* __restrict__ in, float* __restrict__ out) {
    __shared__ float vstate[3][SEQ_PER_BLK];   // v handed stage k -> k+1
    __shared__ unsigned int flag[4];

    const int lane = threadIdx.x & 63;
    const int wk   = threadIdx.x >> 6;         // pipeline stage 0..3

    if (threadIdx.x < 4) flag[threadIdx.x] = 0u;
    __syncthreads();

    // Block handles 64 consecutive sequences; wave k handles their
    // timesteps [wk*64, wk*64+64). seq = blockIdx*64 + lane.
    const uint32_t sgrp  = (uint32_t)blockIdx.x << 6;
    const uint32_t b     = sgrp >> 10;               // batch index
    const uint32_t dbase = sgrp & (D_DIM - 1);       // d range base
    uint32_t voffi = b * (T_STEPS * D_DIM * 4u)
                   + (uint32_t)wk * (TQ * D_DIM * 4u)
                   + (dbase + (uint32_t)lane) * 4u;
    uint32_t voffo = voffi;
    const uint64_t inp_u  = (uint64_t)in;
    const uint64_t outp_u = (uint64_t)out;

    float rA[16], rB[16], rC[16], rD[16];      // this wave's 64 timesteps

    // Issue all 64 loads (cap-throttled past 63 outstanding — harmless),
    // then tanh each slice as it lands. All 4 waves do this in parallel.
    ISSUE16(rA); ISSUE16(rB); ISSUE16(rC); ISSUE16(rD);
    WAITBUF(rA, "48"); TANH16(rA);
    WAITBUF(rB, "32"); TANH16(rB);
    WAITBUF(rC, "16"); TANH16(rC);
    WAITBUF(rD, "0");  TANH16(rD);

    // --- serial section: only the 9-op v-chain, ~0.5us per stage ---
    float v = 0.0f;
    if (wk != 0) {
        while (__hip_atomic_load(&flag[wk - 1], __ATOMIC_ACQUIRE,
                                 __HIP_MEMORY_SCOPE_WORKGROUP) == 0u)
            __builtin_amdgcn_s_sleep(1);
        v = vstate[wk - 1][lane];
    }
    SCAN16(rA); SCAN16(rB); SCAN16(rC); SCAN16(rD);
    if (wk != 3) {
        vstate[wk][lane] = v;
        __hip_atomic_store(&flag[wk], 1u, __ATOMIC_RELEASE,
                           __HIP_MEMORY_SCOPE_WORKGROUP);
    }
    // --- end serial section; stores off the critical chain ---

    STORE16(rA); voffo += 16u * 0x1000u;
    STORE16(rB); voffo += 16u * 0x1000u;
    STORE16(rC); voffo += 16u * 0x1000u;
    STORE16(rD);
}

extern "C" void kernel_launch(void* const* d_in, const int* in_sizes, int n_in,
                              void* d_out, int out_size, void* d_ws, size_t ws_size,
                              hipStream_t stream) {
    const float* in = (const float*)d_in[0];
    float* out = (float*)d_out;
    dim3 block(TPB);
    dim3 grid((B_DIM * D_DIM) / SEQ_PER_BLK);   // 1024 blocks = 4096 waves
    spike_scan_kernel<<<grid, block, 0, stream>>>(in, out);
}